// Round 1
// baseline (115.781 us; speedup 1.0000x reference)
//
#include <hip/hip_runtime.h>
#include <math.h>

// Problem constants (fixed by the reference file)
constexpr int B  = 1024;
constexpr int NL = 64;
constexpr int W  = 2048;
constexpr int INNER = NL - 2;            // layers 1..62 inclusive -> 62 layers
constexpr float EPS_N = 1e-8f;
constexpr float EPS_Y = 1e-9f;
constexpr float TWO_PI = 6.2831853071795864769f;

// One thread per (b, w). Block = 256 consecutive wavelengths of one batch.
// Layer params staged in LDS as float4 (nd, n, 1/(n+eps), unused) so each
// layer costs one broadcast ds_read_b128.
__global__ __launch_bounds__(256)
void tmm_kernel(const float* __restrict__ n_layers,
                const float* __restrict__ d_layers,
                const float* __restrict__ wavelengths,
                float* __restrict__ out)
{
    __shared__ float4 s_layer[INNER];
    __shared__ float s_edge[2];          // n_in, n_sub

    const int b   = blockIdx.y;
    const int tid = threadIdx.x;
    const int w   = blockIdx.x * 256 + tid;

    // Stage per-batch layer parameters (uniform across the block).
    if (tid < INNER) {
        const float n = n_layers[b * NL + 1 + tid];
        const float d = d_layers[b * NL + 1 + tid];
        s_layer[tid] = make_float4(n * d, n, 1.0f / (n + EPS_N), 0.0f);
    }
    if (tid == INNER)     s_edge[0] = n_layers[b * NL];           // n_in
    if (tid == INNER + 1) s_edge[1] = n_layers[b * NL + NL - 1];  // n_sub
    __syncthreads();

    const float k0 = TWO_PI / wavelengths[w];

    // M = [[a, i*bb],[i*cc, dd]] (real a,bb,cc,dd), starts as identity.
    float a = 1.0f, bb = 0.0f, cc = 0.0f, dd = 1.0f;

    #pragma unroll 2
    for (int i = 0; i < INNER; ++i) {
        const float4 L = s_layer[i];
        const float phi = L.x * k0;
        float s, c;
        __sincosf(phi, &s, &c);
        const float ns = L.y * s;        // n*sin(phi)
        const float is = L.z * s;        // sin(phi)/(n+eps)
        const float a2 = fmaf(bb,  ns, a  * c);
        const float b2 = fmaf(-a,  is, bb * c);
        const float c2 = fmaf(-dd, ns, cc * c);
        const float d2 = fmaf(cc,  is, dd * c);
        a = a2; bb = b2; cc = c2; dd = d2;
    }

    const float n_in  = s_edge[0];
    const float n_sub = s_edge[1];

    // E = a + eps_Y + i*(bb*n_sub);  H = dd*n_sub + i*cc
    const float Er = a + EPS_Y;
    const float Ei = bb * n_sub;
    const float Hr = dd * n_sub;
    const float Hi = cc;

    // r = (n_in*E' - H) / (n_in*E' + H);  R = |r|^2
    const float Nr = fmaf(n_in, Er, -Hr);
    const float Ni = fmaf(n_in, Ei, -Hi);
    const float Dr = fmaf(n_in, Er,  Hr);
    const float Di = fmaf(n_in, Ei,  Hi);

    const float R = (Nr * Nr + Ni * Ni) / (Dr * Dr + Di * Di);
    out[b * W + w] = R;
}

extern "C" void kernel_launch(void* const* d_in, const int* in_sizes, int n_in,
                              void* d_out, int out_size, void* d_ws, size_t ws_size,
                              hipStream_t stream)
{
    const float* n_layers    = (const float*)d_in[0];
    const float* d_layers    = (const float*)d_in[1];
    const float* wavelengths = (const float*)d_in[2];
    float* out = (float*)d_out;

    dim3 grid(W / 256, B);
    dim3 block(256);
    tmm_kernel<<<grid, block, 0, stream>>>(n_layers, d_layers, wavelengths, out);
}

// Round 2
// 114.418 us; speedup vs baseline: 1.0119x; 1.0119x over previous
//
#include <hip/hip_runtime.h>
#include <math.h>

// Problem constants (fixed by the reference file)
constexpr int B  = 1024;
constexpr int NL = 64;
constexpr int W  = 2048;
constexpr int INNER = NL - 2;            // layers 1..62 inclusive -> 62 layers
constexpr float EPS_N = 1e-8f;
constexpr float EPS_Y = 1e-9f;

// One thread per (b, w). Block = 256 consecutive wavelengths of one batch.
// Layer params staged in LDS as float4 (n*d, n, 1/(n+eps), pad); broadcast
// ds_read_b128 per layer, software-prefetched one layer ahead.
//
// phi is tracked in REVOLUTIONS: phi_rev = n*d/lambda  (2pi/lambda * 1/2pi),
// so sin/cos are the bare v_sin_f32/v_cos_f32 instructions with zero extra
// range-reduction ops (HW domain >> our max |phi_rev| of ~1.4).
__global__ __launch_bounds__(256)
void tmm_kernel(const float* __restrict__ n_layers,
                const float* __restrict__ d_layers,
                const float* __restrict__ wavelengths,
                float* __restrict__ out)
{
    __shared__ float4 s_layer[INNER + 1];   // +1 pad so prefetch never guards
    __shared__ float s_edge[2];             // n_in, n_sub

    const int b   = blockIdx.y;
    const int tid = threadIdx.x;
    const int w   = blockIdx.x * 256 + tid;

    if (tid < INNER) {
        const float n = n_layers[b * NL + 1 + tid];
        const float d = d_layers[b * NL + 1 + tid];
        s_layer[tid] = make_float4(n * d, n, 1.0f / (n + EPS_N), 0.0f);
    }
    if (tid == INNER) {
        s_layer[INNER] = make_float4(0.f, 0.f, 0.f, 0.f);  // pad entry
        s_edge[0] = n_layers[b * NL];                      // n_in
        s_edge[1] = n_layers[b * NL + NL - 1];             // n_sub
    }
    __syncthreads();

    const float inv_lambda = 1.0f / wavelengths[w];   // = k0 in revolutions

    // M = [[a, i*bb],[i*cc, dd]] (real a,bb,cc,dd), starts as identity.
    float a = 1.0f, bb = 0.0f, cc = 0.0f, dd = 1.0f;

    float4 L = s_layer[0];
    #pragma unroll 2
    for (int i = 0; i < INNER; ++i) {
        const float4 Lnext = s_layer[i + 1];   // prefetch next layer
        const float phi_rev = L.x * inv_lambda;
        const float s = __builtin_amdgcn_sinf(phi_rev);
        const float c = __builtin_amdgcn_cosf(phi_rev);
        const float ns = L.y * s;              // n*sin(phi)
        const float is = L.z * s;              // sin(phi)/(n+eps)
        const float a2 = fmaf(bb,  ns, a  * c);
        const float b2 = fmaf(-a,  is, bb * c);
        const float c2 = fmaf(-dd, ns, cc * c);
        const float d2 = fmaf(cc,  is, dd * c);
        a = a2; bb = b2; cc = c2; dd = d2;
        L = Lnext;
    }

    const float n_in  = s_edge[0];
    const float n_sub = s_edge[1];

    // E = a + eps_Y + i*(bb*n_sub);  H = dd*n_sub + i*cc
    const float Er = a + EPS_Y;
    const float Ei = bb * n_sub;
    const float Hr = dd * n_sub;
    const float Hi = cc;

    const float Nr = fmaf(n_in, Er, -Hr);
    const float Ni = fmaf(n_in, Ei, -Hi);
    const float Dr = fmaf(n_in, Er,  Hr);
    const float Di = fmaf(n_in, Ei,  Hi);

    const float R = (Nr * Nr + Ni * Ni) / (Dr * Dr + Di * Di);
    out[b * W + w] = R;
}

extern "C" void kernel_launch(void* const* d_in, const int* in_sizes, int n_in,
                              void* d_out, int out_size, void* d_ws, size_t ws_size,
                              hipStream_t stream)
{
    const float* n_layers    = (const float*)d_in[0];
    const float* d_layers    = (const float*)d_in[1];
    const float* wavelengths = (const float*)d_in[2];
    float* out = (float*)d_out;

    dim3 grid(W / 256, B);
    dim3 block(256);
    tmm_kernel<<<grid, block, 0, stream>>>(n_layers, d_layers, wavelengths, out);
}

// Round 3
// 104.120 us; speedup vs baseline: 1.1120x; 1.0989x over previous
//
#include <hip/hip_runtime.h>
#include <math.h>

// Problem constants (fixed by the reference file)
constexpr int B  = 1024;
constexpr int NL = 64;
constexpr int W  = 2048;
constexpr int INNER = NL - 2;            // layers 1..62 inclusive -> 62 layers
constexpr float EPS_N = 1e-8f;
constexpr float EPS_Y = 1e-9f;

typedef float v2f __attribute__((ext_vector_type(2)));

// One thread per (b, w). Block = 256 consecutive wavelengths of one batch.
//
// phi tracked in REVOLUTIONS (v_sin_f32/v_cos_f32 take revolutions*2pi), so
// phi_rev = n*d/lambda and sin/cos are single trans instructions.
//
// The 2x2 complex transfer matrix stays in the real form [[a, i*b],[i*c, d]];
// packed as two float2 chains p=(a,c), q=(b,d) so the per-layer update is
// 4 v_pk_{mul,fma}_f32 (double-rate FP32) instead of 8 scalar ops:
//   p' = q*(ns,-ns) + p*c ;  q' = p_old*(-is,is) + q*c
// LDS layer record: (n*d, n, -n, 1/(n+eps)) so (ns,-ns) is one pk_mul of
// adjacent VGPRs from the ds_read_b128.
__global__ __launch_bounds__(256)
void tmm_kernel(const float* __restrict__ n_layers,
                const float* __restrict__ d_layers,
                const float* __restrict__ wavelengths,
                float* __restrict__ out)
{
    __shared__ float4 s_layer[INNER];
    __shared__ float s_edge[2];             // n_in, n_sub

    const int b   = blockIdx.y;
    const int tid = threadIdx.x;
    const int w   = blockIdx.x * 256 + tid;

    if (tid < INNER) {
        const float n = n_layers[b * NL + 1 + tid];
        const float d = d_layers[b * NL + 1 + tid];
        s_layer[tid] = make_float4(n * d, n, -n, 1.0f / (n + EPS_N));
    }
    if (tid == INNER) {
        s_edge[0] = n_layers[b * NL];                      // n_in
        s_edge[1] = n_layers[b * NL + NL - 1];             // n_sub
    }
    __syncthreads();

    const float inv_lambda = 1.0f / wavelengths[w];   // k0 in revolutions

    // p = (a, c), q = (b, d); M = [[a, i*b],[i*c, d]] starts as identity.
    v2f p = {1.0f, 0.0f};
    v2f q = {0.0f, 1.0f};

    #pragma unroll
    for (int i = 0; i < INNER; ++i) {
        const float4 L = s_layer[i];
        const float phi_rev = L.x * inv_lambda;
        const float s = __builtin_amdgcn_sinf(phi_rev);
        const float c = __builtin_amdgcn_cosf(phi_rev);

        const v2f nn  = {L.y, L.z};           // (n, -n): adjacent VGPRs
        const v2f ss  = {s, s};
        const v2f ns2 = nn * ss;              // (n*s, -n*s): one v_pk_mul
        const float is = L.w * s;             // s/(n+eps)
        const v2f is2 = {-is, is};            // fnegs fold into pk modifiers
        const v2f c2  = {c, c};

        const v2f pold = p;
        p = __builtin_elementwise_fma(q,    ns2, p * c2);
        q = __builtin_elementwise_fma(pold, is2, q * c2);
    }

    const float a  = p.x;
    const float cc = p.y;
    const float bb = q.x;
    const float dd = q.y;

    const float n_in  = s_edge[0];
    const float n_sub = s_edge[1];

    // E = a + eps_Y + i*(bb*n_sub);  H = dd*n_sub + i*cc
    const float Er = a + EPS_Y;
    const float Ei = bb * n_sub;
    const float Hr = dd * n_sub;
    const float Hi = cc;

    const float Nr = fmaf(n_in, Er, -Hr);
    const float Ni = fmaf(n_in, Ei, -Hi);
    const float Dr = fmaf(n_in, Er,  Hr);
    const float Di = fmaf(n_in, Ei,  Hi);

    const float R = (Nr * Nr + Ni * Ni) / (Dr * Dr + Di * Di);
    out[b * W + w] = R;
}

extern "C" void kernel_launch(void* const* d_in, const int* in_sizes, int n_in,
                              void* d_out, int out_size, void* d_ws, size_t ws_size,
                              hipStream_t stream)
{
    const float* n_layers    = (const float*)d_in[0];
    const float* d_layers    = (const float*)d_in[1];
    const float* wavelengths = (const float*)d_in[2];
    float* out = (float*)d_out;

    dim3 grid(W / 256, B);
    dim3 block(256);
    tmm_kernel<<<grid, block, 0, stream>>>(n_layers, d_layers, wavelengths, out);
}